// Round 1
// baseline (13602.119 us; speedup 1.0000x reference)
//
#include <hip/hip_runtime.h>

#define B_ 256
#define T_ 256
#define H_ 300
#define IN_ 16
#define NT_ 75          // N tiles (1200/16)
#define KS0_ 10         // K slabs layer0 (320/32): [h 300 | x 16 | pad 4]
#define KS1_ 19         // K slabs layer1 (608/32): [h1 300 | h0 300 | pad 8]

typedef __attribute__((ext_vector_type(8))) short short8;
typedef __attribute__((ext_vector_type(4))) float f32x4;
typedef unsigned int uint32;

__device__ __forceinline__ unsigned short f2bf(float f) {
    uint32 u = __float_as_uint(f);
    u = u + 0x7fffu + ((u >> 16) & 1u);   // RNE
    return (unsigned short)(u >> 16);
}
__device__ __forceinline__ float bf2f(unsigned short h) {
    return __uint_as_float(((uint32)h) << 16);
}
__device__ __forceinline__ float sigm(float x) { return 1.f / (1.f + __expf(-x)); }
__device__ __forceinline__ float tanh_f(float x) {
    float xc = fminf(fmaxf(x, -15.f), 15.f);
    float e = __expf(2.f * xc);
    return (e - 1.f) / (e + 1.f);
}

// ---------------------------------------------------------------------------
// Weight packing: bf16 MFMA fragments, gate rows permuted unit-major.
// Packed row p = 4*jj + gamma  <->  original row r = gamma*300 + jj.
// Fragment (A-operand of mfma_f32_16x16x32_bf16):
//   pack[(tile*KS + slab)*64 + lane] (16B) = W'[tile*16 + (lane&15)][slab*32 + (lane>>4)*8 + 0..7]
// ---------------------------------------------------------------------------
__global__ void pack_kernel(const float* __restrict__ Wih0, const float* __restrict__ Whh0,
                            const float* __restrict__ bih0, const float* __restrict__ bhh0,
                            const float* __restrict__ Wih1, const float* __restrict__ Whh1,
                            const float* __restrict__ bih1, const float* __restrict__ bhh1,
                            uint32* __restrict__ w0p, uint32* __restrict__ w1p,
                            float* __restrict__ b0p, float* __restrict__ b1p)
{
    const int NW0 = NT_ * KS0_ * 64;   // 48000
    const int NW1 = NT_ * KS1_ * 64;   // 91200
    int id = blockIdx.x * blockDim.x + threadIdx.x;
    if (id < NW0) {
        int lane = id & 63, ts = id >> 6;
        int slab = ts % KS0_, tile = ts / KS0_;
        int rp = tile * 16 + (lane & 15);
        int jj = rp >> 2, g = rp & 3;
        int r = g * H_ + jj;
        int kb = slab * 32 + (lane >> 4) * 8;
        #pragma unroll
        for (int p = 0; p < 4; ++p) {
            int k0 = kb + 2 * p, k1 = k0 + 1;
            float v0 = (k0 < H_) ? Whh0[r * H_ + k0] : ((k0 < H_ + IN_) ? Wih0[r * IN_ + (k0 - H_)] : 0.f);
            float v1 = (k1 < H_) ? Whh0[r * H_ + k1] : ((k1 < H_ + IN_) ? Wih0[r * IN_ + (k1 - H_)] : 0.f);
            w0p[id * 4 + p] = (uint32)f2bf(v0) | ((uint32)f2bf(v1) << 16);
        }
    } else if (id < NW0 + NW1) {
        int id2 = id - NW0;
        int lane = id2 & 63, ts = id2 >> 6;
        int slab = ts % KS1_, tile = ts / KS1_;
        int rp = tile * 16 + (lane & 15);
        int jj = rp >> 2, g = rp & 3;
        int r = g * H_ + jj;
        int kb = slab * 32 + (lane >> 4) * 8;
        #pragma unroll
        for (int p = 0; p < 4; ++p) {
            int k0 = kb + 2 * p, k1 = k0 + 1;
            float v0 = (k0 < H_) ? Whh1[r * H_ + k0] : ((k0 < 2 * H_) ? Wih1[r * H_ + (k0 - H_)] : 0.f);
            float v1 = (k1 < H_) ? Whh1[r * H_ + k1] : ((k1 < 2 * H_) ? Wih1[r * H_ + (k1 - H_)] : 0.f);
            w1p[id2 * 4 + p] = (uint32)f2bf(v0) | ((uint32)f2bf(v1) << 16);
        }
    } else if (id < NW0 + NW1 + 1200) {
        int p = id - (NW0 + NW1);
        int jj = p >> 2, g = p & 3, r = g * H_ + jj;
        b0p[p] = bih0[r] + bhh0[r];
    } else if (id < NW0 + NW1 + 2400) {
        int p = id - (NW0 + NW1 + 1200);
        int jj = p >> 2, g = p & 3, r = g * H_ + jj;
        b1p[p] = bih1[r] + bhh1[r];
    }
}

// ---------------------------------------------------------------------------
// State staging into fragment-ordered LDS buffer.
// Element k of the state vector for batch row m lives at:
//   Ab[((k>>5)*64 + ((k>>3)&3)*16 + m)*8 + (k&7)]
// ---------------------------------------------------------------------------
template<int LAYER>
__device__ __forceinline__ void stage(const void* inptr, int b0, int t,
                                      unsigned short* Ab, int tid)
{
    if constexpr (LAYER == 0) {
        if (tid < 256) {
            int m = tid >> 4, xi = tid & 15;
            const float* x = (const float*)inptr;
            float v = x[((b0 + m) * T_ + t) * IN_ + xi];
            int k = H_ + xi;                       // 300..315
            int slab = k >> 5, kk = k & 31, oct = kk >> 3, e = kk & 7;
            Ab[((slab * 64 + oct * 16 + m) << 3) + e] = f2bf(v);
        }
    } else {
        const uint32* h0 = (const uint32*)inptr;   // bf16 pairs
        for (int it = tid; it < 16 * 150; it += 512) {
            int m = it / 150, pr = it % 150;
            uint32 v = h0[((b0 + m) * T_ + t) * 150 + pr];
            int k = H_ + 2 * pr;                   // 300..598, even
            int slab = k >> 5, kk = k & 31, oct = kk >> 3, e = kk & 7;
            *(uint32*)&Ab[((slab * 64 + oct * 16 + m) << 3) + e] = v;
        }
    }
}

// ---------------------------------------------------------------------------
// Persistent per-batch-group LSTM layer. 16 blocks x 512 threads.
// Each block owns 16 batch rows for all 256 timesteps; no inter-block comm.
// ---------------------------------------------------------------------------
template<int LAYER>
__global__ __launch_bounds__(512, 2) void lstm_kernel(
    const void* __restrict__ inptr, const short8* __restrict__ wp,
    const float* __restrict__ biasp, unsigned short* __restrict__ hout)
{
    constexpr int KS = (LAYER == 0) ? KS0_ : KS1_;
    __shared__ alignas(16) unsigned short Abuf[2][KS * 512];
    __shared__ alignas(16) float biasLds[1200];

    const int tid = threadIdx.x;
    const int wave = tid >> 6;
    const int lane = tid & 63;
    const int b0 = blockIdx.x * 16;

    {   // zero both A buffers (pads must be 0; h slots = h_{-1} = 0)
        uint32* az = (uint32*)&Abuf[0][0];
        for (int i = tid; i < KS * 512; i += 512) az[i] = 0u;
        for (int i = tid; i < 1200; i += 512) biasLds[i] = biasp[i];
    }
    __syncthreads();

    stage<LAYER>(inptr, b0, 0, &Abuf[0][0], tid);

    float c[10];
    #pragma unroll
    for (int i = 0; i < 10; ++i) c[i] = 0.f;

    int cur = 0;
    for (int t = 0; t < T_; ++t) {
        __syncthreads();   // Abuf[cur] fully written (stage + prev h writes)

        if (t + 1 < T_) stage<LAYER>(inptr, b0, t + 1, &Abuf[cur ^ 1][0], tid);

        // hoist state fragments for this step (lane-contiguous ds_read_b128)
        short8 a[KS];
        const short8* ap = (const short8*)&Abuf[cur][0];
        #pragma unroll
        for (int s = 0; s < KS; ++s) a[s] = ap[s * 64 + lane];

        #pragma unroll
        for (int ti = 0; ti < 10; ++ti) {
            int n = wave + 8 * ti;
            if (n < NT_) {
                f32x4 acc = {0.f, 0.f, 0.f, 0.f};
                #pragma unroll
                for (int s = 0; s < KS; ++s) {
                    short8 w = wp[(n * KS + s) * 64 + lane];
                    acc = __builtin_amdgcn_mfma_f32_16x16x32_bf16(w, a[s], acc, 0, 0, 0);
                }
                // lane holds (i,f,g,o) of unit jj for batch row m
                const f32x4 b4 = *(const f32x4*)&biasLds[n * 16 + (lane >> 4) * 4];
                float gi = sigm(acc[0] + b4[0]);
                float gf = sigm(acc[1] + b4[1]);
                float gg = tanh_f(acc[2] + b4[2]);
                float go = sigm(acc[3] + b4[3]);
                float cn = gf * c[ti] + gi * gg;
                c[ti] = cn;
                float h = go * tanh_f(cn);
                unsigned short hb = f2bf(h);
                int jj = n * 4 + (lane >> 4);
                int m = lane & 15;
                Abuf[cur ^ 1][(((jj >> 5) * 64 + ((jj >> 3) & 3) * 16 + m) << 3) + (jj & 7)] = hb;
                hout[((b0 + m) * T_ + t) * H_ + jj] = hb;
            }
        }
        cur ^= 1;
    }
}

// ---------------------------------------------------------------------------
// MLP head: per-thread position, weights read uniformly (scalar-cached).
// ---------------------------------------------------------------------------
__global__ __launch_bounds__(256) void head_kernel(
    const unsigned short* __restrict__ h1,
    const float* __restrict__ W1, const float* __restrict__ b1,
    const float* __restrict__ W2, const float* __restrict__ b2,
    const float* __restrict__ W3, const float* __restrict__ b3,
    float* __restrict__ out)
{
    int pos = blockIdx.x * 256 + threadIdx.x;
    const unsigned short* hr = h1 + pos * H_;
    float t1[30];
    #pragma unroll
    for (int j = 0; j < 30; ++j) t1[j] = b1[j];
    for (int kc = 0; kc < H_; kc += 4) {
        uint32 u0 = *(const uint32*)(hr + kc);
        uint32 u1 = *(const uint32*)(hr + kc + 2);
        float h0v = bf2f((unsigned short)(u0 & 0xffffu));
        float h1v = bf2f((unsigned short)(u0 >> 16));
        float h2v = bf2f((unsigned short)(u1 & 0xffffu));
        float h3v = bf2f((unsigned short)(u1 >> 16));
        #pragma unroll
        for (int j = 0; j < 30; ++j) {
            const float* wr = W1 + j * H_ + kc;
            t1[j] += h0v * wr[0] + h1v * wr[1] + h2v * wr[2] + h3v * wr[3];
        }
    }
    #pragma unroll
    for (int j = 0; j < 30; ++j) t1[j] = tanh_f(t1[j]);
    float oacc = b3[0];
    for (int j2 = 0; j2 < 100; ++j2) {
        float a2 = b2[j2];
        #pragma unroll
        for (int k = 0; k < 30; ++k) a2 += t1[k] * W2[j2 * 30 + k];
        oacc += tanh_f(a2) * W3[j2];
    }
    out[pos] = sigm(oacc);
}

// ---------------------------------------------------------------------------
extern "C" void kernel_launch(void* const* d_in, const int* in_sizes, int n_in,
                              void* d_out, int out_size, void* d_ws, size_t ws_size,
                              hipStream_t stream)
{
    const float* x    = (const float*)d_in[0];
    const float* Wih0 = (const float*)d_in[1];
    const float* Whh0 = (const float*)d_in[2];
    const float* bih0 = (const float*)d_in[3];
    const float* bhh0 = (const float*)d_in[4];
    const float* Wih1 = (const float*)d_in[5];
    const float* Whh1 = (const float*)d_in[6];
    const float* bih1 = (const float*)d_in[7];
    const float* bhh1 = (const float*)d_in[8];
    const float* W1   = (const float*)d_in[9];
    const float* b1   = (const float*)d_in[10];
    const float* W2   = (const float*)d_in[11];
    const float* b2   = (const float*)d_in[12];
    const float* W3   = (const float*)d_in[13];
    const float* b3   = (const float*)d_in[14];

    char* ws = (char*)d_ws;
    const size_t OFF_W0 = 0;
    const size_t OFF_W1 = (size_t)1 << 20;
    const size_t OFF_B0 = (size_t)3 << 20;
    const size_t OFF_B1 = ((size_t)3 << 20) + 8192;
    const size_t OFF_H0 = (size_t)4 << 20;
    const size_t HBYTES = (size_t)B_ * T_ * H_ * 2;           // 39321600
    const size_t OFF_H1 = OFF_H0 + HBYTES;
    const size_t NEED   = OFF_H1 + HBYTES;                    // ~79 MB
    if (ws_size < NEED) return;  // avoid corrupting memory if ws too small

    uint32* w0p = (uint32*)(ws + OFF_W0);
    uint32* w1p = (uint32*)(ws + OFF_W1);
    float*  b0p = (float*)(ws + OFF_B0);
    float*  b1p = (float*)(ws + OFF_B1);
    unsigned short* h0b = (unsigned short*)(ws + OFF_H0);
    unsigned short* h1b = (unsigned short*)(ws + OFF_H1);

    int packWork = NT_ * KS0_ * 64 + NT_ * KS1_ * 64 + 2400;
    hipLaunchKernelGGL(pack_kernel, dim3((packWork + 255) / 256), dim3(256), 0, stream,
                       Wih0, Whh0, bih0, bhh0, Wih1, Whh1, bih1, bhh1, w0p, w1p, b0p, b1p);
    hipLaunchKernelGGL((lstm_kernel<0>), dim3(16), dim3(512), 0, stream,
                       (const void*)x, (const short8*)w0p, b0p, h0b);
    hipLaunchKernelGGL((lstm_kernel<1>), dim3(16), dim3(512), 0, stream,
                       (const void*)h0b, (const short8*)w1p, b1p, h1b);
    hipLaunchKernelGGL(head_kernel, dim3(256), dim3(256), 0, stream,
                       h1b, W1, b1, W2, b2, W3, b3, (float*)d_out);
}

// Round 2
// 12786.275 us; speedup vs baseline: 1.0638x; 1.0638x over previous
//
#include <hip/hip_runtime.h>

#define B_ 256
#define T_ 256
#define H_ 300
#define IN_ 16
#define NT_ 75          // gate tiles (1200/16)
#define KSR_ 10         // recurrent K slabs (300 -> 320)
#define HP_ 320         // padded h row stride (elements)

typedef __attribute__((ext_vector_type(8))) short short8;
typedef __attribute__((ext_vector_type(4))) float f32x4;
typedef unsigned int uint32;

__device__ __forceinline__ unsigned short f2bf(float f) {
    uint32 u = __float_as_uint(f);
    u = u + 0x7fffu + ((u >> 16) & 1u);   // RNE
    return (unsigned short)(u >> 16);
}
__device__ __forceinline__ float bf2f(unsigned short h) {
    return __uint_as_float(((uint32)h) << 16);
}
__device__ __forceinline__ float sigm(float x) {
    float e = __expf(-x);
    return __builtin_amdgcn_rcpf(1.f + e);
}
__device__ __forceinline__ float tanh_f(float x) {
    float xc = fminf(fmaxf(x, -15.f), 15.f);
    float e = __expf(2.f * xc);
    return (e - 1.f) * __builtin_amdgcn_rcpf(e + 1.f);
}

// ---------------------------------------------------------------------------
// Weight packing into bf16 MFMA A-fragments, gate rows permuted unit-major.
// Packed row p = 4*jj + gamma  <->  original row r = gamma*300 + jj.
// frag[(tile*KS + slab)*64 + lane] (16B) = W'[tile*16+(lane&15)][slab*32+(lane>>4)*8 + 0..7]
// ---------------------------------------------------------------------------
__device__ __forceinline__ void pack_one(int idx, const float* __restrict__ W,
                                         int K, int KS, uint32* __restrict__ dst)
{
    int lane = idx & 63, ts = idx >> 6;
    int slab = ts % KS, tile = ts / KS;
    int rp = tile * 16 + (lane & 15);
    int jj = rp >> 2, g = rp & 3;
    int r = g * H_ + jj;
    int kb = slab * 32 + (lane >> 4) * 8;
    #pragma unroll
    for (int p = 0; p < 4; ++p) {
        int k0 = kb + 2 * p, k1 = k0 + 1;
        float v0 = (k0 < K) ? W[(size_t)r * K + k0] : 0.f;
        float v1 = (k1 < K) ? W[(size_t)r * K + k1] : 0.f;
        dst[(size_t)idx * 4 + p] = (uint32)f2bf(v0) | ((uint32)f2bf(v1) << 16);
    }
}

__global__ void pack_kernel(const float* __restrict__ Wih0, const float* __restrict__ Whh0,
                            const float* __restrict__ bih0, const float* __restrict__ bhh0,
                            const float* __restrict__ Wih1, const float* __restrict__ Whh1,
                            const float* __restrict__ bih1, const float* __restrict__ bhh1,
                            uint32* __restrict__ wr0, uint32* __restrict__ wg0,
                            uint32* __restrict__ wr1, uint32* __restrict__ wg1,
                            float* __restrict__ b0p, float* __restrict__ b1p)
{
    const int C0 = NT_ * KSR_ * 64;   // 48000
    const int C1 = NT_ * 64;          // 4800
    int id = blockIdx.x * 256 + threadIdx.x;
    if (id < C0) pack_one(id, Whh0, H_, KSR_, wr0);
    else if (id < C0 + C1) pack_one(id - C0, Wih0, IN_, 1, wg0);
    else if (id < 2 * C0 + C1) pack_one(id - C0 - C1, Whh1, H_, KSR_, wr1);
    else if (id < 3 * C0 + C1) pack_one(id - 2 * C0 - C1, Wih1, H_, KSR_, wg1);
    else if (id < 3 * C0 + C1 + 1200) {
        int p = id - 3 * C0 - C1;
        int jj = p >> 2, g = p & 3, r = g * H_ + jj;
        b0p[p] = bih0[r] + bhh0[r];
    } else if (id < 3 * C0 + C1 + 2400) {
        int p = id - 3 * C0 - C1 - 1200;
        int jj = p >> 2, g = p & 3, r = g * H_ + jj;
        b1p[p] = bih1[r] + bhh1[r];
    }
}

// ---------------------------------------------------------------------------
// xg GEMM: xg[(g*TC+tc)*NT + n][lane] (f32x4, MFMA C-frag layout) =
//          bias + Wih @ input_t   for batch group g, chunk-local step tc.
// L0: input = x (f32, K=16).  L1: input = h0c (bf16, stride HP_, K=300).
// ---------------------------------------------------------------------------
template<int LAYER>
__global__ __launch_bounds__(256) void gemm_xg(
    const float* __restrict__ x, const unsigned short* __restrict__ hin,
    const short8* __restrict__ wgp, const float* __restrict__ bp,
    f32x4* __restrict__ xg, int t0, int TC)
{
    constexpr int KS = (LAYER == 0) ? 1 : KSR_;
    const int tc = blockIdx.x, g = blockIdx.y;
    const int wave = threadIdx.x >> 6, lane = threadIdx.x & 63;
    const int m = lane & 15, oct = lane >> 4;

    short8 a[KS];
    if constexpr (LAYER == 0) {
        if (oct < 2) {
            const float* xr = x + ((size_t)(g * 16 + m) * T_ + (t0 + tc)) * IN_ + oct * 8;
            short8 v;
            #pragma unroll
            for (int e = 0; e < 8; ++e) v[e] = (short)f2bf(xr[e]);
            a[0] = v;
        } else {
            short8 z = {0, 0, 0, 0, 0, 0, 0, 0};
            a[0] = z;
        }
    } else {
        const unsigned short* hr = hin + ((size_t)(g * 16 + m) * TC + tc) * HP_ + oct * 8;
        #pragma unroll
        for (int s = 0; s < KS; ++s) a[s] = *(const short8*)(hr + s * 32);
    }

    f32x4* xq = xg + ((size_t)g * TC + tc) * NT_ * 64;
    #pragma unroll
    for (int ti = 0; ti < 19; ++ti) {
        int n = wave + 4 * ti;
        if (n >= NT_) continue;
        f32x4 acc = *(const f32x4*)&bp[n * 16 + oct * 4];
        #pragma unroll
        for (int s = 0; s < KS; ++s)
            acc = __builtin_amdgcn_mfma_f32_16x16x32_bf16(wgp[((size_t)n * KS + s) * 64 + lane],
                                                          a[s], acc, 0, 0, 0);
        xq[(size_t)n * 64 + lane] = acc;
    }
}

// ---------------------------------------------------------------------------
// Recurrent LSTM chunk: 16 blocks x 1024 threads, block = 16 batch rows.
// Only h @ Whh per step (10 slabs); xg precomputed, prefetched next-step.
// ---------------------------------------------------------------------------
__global__ __launch_bounds__(1024) void lstm_rec(
    const short8* __restrict__ wp, const f32x4* __restrict__ xg,
    unsigned short* __restrict__ hout, float* __restrict__ cbuf,
    uint32* __restrict__ hstate, int t0, int TC, size_t rowstride_b, int tbase)
{
    __shared__ alignas(16) unsigned short Abuf[2][KSR_ * 512];   // 2 x 10KB
    const int tid = threadIdx.x;
    const int wave = tid >> 6, lane = tid & 63;
    const int g = blockIdx.x;
    const int b0 = g * 16;
    const int m = lane & 15;

    // init recurrent state (pads in both buffers must be 0; never re-written)
    if (t0 == 0) {
        uint32* az = (uint32*)&Abuf[0][0];
        for (int i = tid; i < 2 * 2560; i += 1024) az[i] = 0u;
    } else {
        uint32* a0 = (uint32*)&Abuf[0][0];
        uint32* a1 = (uint32*)&Abuf[1][0];
        const uint32* hs = hstate + (size_t)g * 2560;
        for (int i = tid; i < 2560; i += 1024) { a0[i] = hs[i]; a1[i] = 0u; }
    }
    float c[5];
    #pragma unroll
    for (int ti = 0; ti < 5; ++ti) {
        int n = wave + 16 * ti;
        c[ti] = (t0 == 0 || n >= NT_) ? 0.f : cbuf[((size_t)g * NT_ + n) * 64 + lane];
    }
    const f32x4* xgp = xg + (size_t)g * TC * NT_ * 64;
    __syncthreads();

    f32x4 xgv[5];
    #pragma unroll
    for (int ti = 0; ti < 5; ++ti) {
        int n = wave + 16 * ti;
        if (n < NT_) xgv[ti] = xgp[(size_t)n * 64 + lane];
    }

    int cur = 0;
    for (int tc = 0; tc < TC; ++tc) {
        short8 a[KSR_];
        const short8* ap = (const short8*)&Abuf[cur][0];
        #pragma unroll
        for (int s = 0; s < KSR_; ++s) a[s] = ap[s * 64 + lane];

        f32x4 xgn[5];
        if (tc + 1 < TC) {
            const f32x4* xq = xgp + (size_t)(tc + 1) * NT_ * 64;
            #pragma unroll
            for (int ti = 0; ti < 5; ++ti) {
                int n = wave + 16 * ti;
                if (n < NT_) xgn[ti] = xq[(size_t)n * 64 + lane];
            }
        }

        #pragma unroll
        for (int ti = 0; ti < 5; ++ti) {
            int n = wave + 16 * ti;
            if (n >= NT_) continue;
            f32x4 acc = {0.f, 0.f, 0.f, 0.f};
            const short8* wq = wp + (size_t)n * KSR_ * 64 + lane;
            #pragma unroll
            for (int s = 0; s < KSR_; ++s)
                acc = __builtin_amdgcn_mfma_f32_16x16x32_bf16(wq[s * 64], a[s], acc, 0, 0, 0);
            float gi = sigm(acc[0] + xgv[ti][0]);
            float gf = sigm(acc[1] + xgv[ti][1]);
            float gg = tanh_f(acc[2] + xgv[ti][2]);
            float go = sigm(acc[3] + xgv[ti][3]);
            float cn = gf * c[ti] + gi * gg;
            c[ti] = cn;
            unsigned short hb = f2bf(go * tanh_f(cn));
            int jj = n * 4 + (lane >> 4);
            Abuf[cur ^ 1][(((jj >> 5) * 64 + ((jj >> 3) & 3) * 16 + m) << 3) + (jj & 7)] = hb;
            hout[(size_t)(b0 + m) * rowstride_b + (size_t)(tbase + tc) * HP_ + jj] = hb;
        }
        __syncthreads();
        if (tc + 1 < TC) {
            #pragma unroll
            for (int ti = 0; ti < 5; ++ti) xgv[ti] = xgn[ti];
        }
        cur ^= 1;
    }

    // dump state for next chunk
    uint32* hd = hstate + (size_t)g * 2560;
    const uint32* asrc = (const uint32*)&Abuf[cur][0];
    for (int i = tid; i < 2560; i += 1024) hd[i] = asrc[i];
    #pragma unroll
    for (int ti = 0; ti < 5; ++ti) {
        int n = wave + 16 * ti;
        if (n < NT_) cbuf[((size_t)g * NT_ + n) * 64 + lane] = c[ti];
    }
}

// ---------------------------------------------------------------------------
// MLP head: per-thread position; weights uniform (L1/L2-cached).
// ---------------------------------------------------------------------------
__global__ __launch_bounds__(256) void head_kernel(
    const unsigned short* __restrict__ h1,
    const float* __restrict__ W1, const float* __restrict__ b1,
    const float* __restrict__ W2, const float* __restrict__ b2,
    const float* __restrict__ W3, const float* __restrict__ b3,
    float* __restrict__ out)
{
    int pos = blockIdx.x * 256 + threadIdx.x;
    const unsigned short* hr = h1 + (size_t)pos * HP_;
    float t1[30];
    #pragma unroll
    for (int j = 0; j < 30; ++j) t1[j] = b1[j];
    for (int kc = 0; kc < H_; kc += 4) {
        uint32 u0 = *(const uint32*)(hr + kc);
        uint32 u1 = *(const uint32*)(hr + kc + 2);
        float h0v = bf2f((unsigned short)(u0 & 0xffffu));
        float h1v = bf2f((unsigned short)(u0 >> 16));
        float h2v = bf2f((unsigned short)(u1 & 0xffffu));
        float h3v = bf2f((unsigned short)(u1 >> 16));
        #pragma unroll
        for (int j = 0; j < 30; ++j) {
            const float* wr = W1 + j * H_ + kc;
            t1[j] += h0v * wr[0] + h1v * wr[1] + h2v * wr[2] + h3v * wr[3];
        }
    }
    #pragma unroll
    for (int j = 0; j < 30; ++j) t1[j] = tanh_f(t1[j]);
    float oacc = b3[0];
    for (int j2 = 0; j2 < 100; ++j2) {
        float a2 = b2[j2];
        #pragma unroll
        for (int k = 0; k < 30; ++k) a2 += t1[k] * W2[j2 * 30 + k];
        oacc += tanh_f(a2) * W3[j2];
    }
    out[pos] = sigm(oacc);
}

// ---------------------------------------------------------------------------
extern "C" void kernel_launch(void* const* d_in, const int* in_sizes, int n_in,
                              void* d_out, int out_size, void* d_ws, size_t ws_size,
                              hipStream_t stream)
{
    const float* x    = (const float*)d_in[0];
    const float* Wih0 = (const float*)d_in[1];
    const float* Whh0 = (const float*)d_in[2];
    const float* bih0 = (const float*)d_in[3];
    const float* bhh0 = (const float*)d_in[4];
    const float* Wih1 = (const float*)d_in[5];
    const float* Whh1 = (const float*)d_in[6];
    const float* bih1 = (const float*)d_in[7];
    const float* bhh1 = (const float*)d_in[8];
    const float* W1   = (const float*)d_in[9];
    const float* b1   = (const float*)d_in[10];
    const float* W2   = (const float*)d_in[11];
    const float* b2   = (const float*)d_in[12];
    const float* W3   = (const float*)d_in[13];
    const float* b3   = (const float*)d_in[14];

    char* ws = (char*)d_ws;
    const size_t OFF_WR0 = 0;
    const size_t OFF_WG0 = 0x100000;
    const size_t OFF_WR1 = 0x200000;
    const size_t OFF_WG1 = 0x300000;
    const size_t OFF_B0  = 0x400000;
    const size_t OFF_B1  = 0x402000;
    const size_t OFF_CB0 = 0x500000;
    const size_t OFF_CB1 = 0x580000;
    const size_t OFF_HS0 = 0x600000;
    const size_t OFF_HS1 = 0x640000;
    const size_t OFF_H1  = 0x700000;
    const size_t H1_BYTES = (size_t)B_ * T_ * HP_ * 2;   // 40 MiB
    const size_t OFF_H0C  = OFF_H1 + H1_BYTES;

    int TC = 0;
    {
        const int cands[4] = {64, 32, 16, 8};
        for (int i = 0; i < 4; ++i) {
            size_t h0cb = (size_t)B_ * cands[i] * HP_ * 2;
            size_t xgb  = (size_t)16 * cands[i] * NT_ * 64 * 16;
            if (OFF_H0C + h0cb + xgb <= ws_size) { TC = cands[i]; break; }
        }
    }
    if (TC == 0) return;
    const size_t OFF_XG = OFF_H0C + (size_t)B_ * TC * HP_ * 2;

    uint32* wr0 = (uint32*)(ws + OFF_WR0);
    uint32* wg0 = (uint32*)(ws + OFF_WG0);
    uint32* wr1 = (uint32*)(ws + OFF_WR1);
    uint32* wg1 = (uint32*)(ws + OFF_WG1);
    float*  b0p = (float*)(ws + OFF_B0);
    float*  b1p = (float*)(ws + OFF_B1);
    float*  cb0 = (float*)(ws + OFF_CB0);
    float*  cb1 = (float*)(ws + OFF_CB1);
    uint32* hs0 = (uint32*)(ws + OFF_HS0);
    uint32* hs1 = (uint32*)(ws + OFF_HS1);
    unsigned short* h1b = (unsigned short*)(ws + OFF_H1);
    unsigned short* h0c = (unsigned short*)(ws + OFF_H0C);
    f32x4* xgb = (f32x4*)(ws + OFF_XG);

    // zero h0c once per launch (pads must be finite/zero for gemm1 slab-9 reads)
    hipMemsetAsync(ws + OFF_H0C, 0, (size_t)B_ * TC * HP_ * 2, stream);

    hipLaunchKernelGGL(pack_kernel, dim3(591), dim3(256), 0, stream,
                       Wih0, Whh0, bih0, bhh0, Wih1, Whh1, bih1, bhh1,
                       wr0, wg0, wr1, wg1, b0p, b1p);

    for (int t0 = 0; t0 < T_; t0 += TC) {
        hipLaunchKernelGGL((gemm_xg<0>), dim3(TC, 16), dim3(256), 0, stream,
                           x, (const unsigned short*)nullptr, (const short8*)wg0, b0p, xgb, t0, TC);
        hipLaunchKernelGGL(lstm_rec, dim3(16), dim3(1024), 0, stream,
                           (const short8*)wr0, (const f32x4*)xgb, h0c, cb0, hs0,
                           t0, TC, (size_t)TC * HP_, 0);
        hipLaunchKernelGGL((gemm_xg<1>), dim3(TC, 16), dim3(256), 0, stream,
                           (const float*)nullptr, h0c, (const short8*)wg1, b1p, xgb, t0, TC);
        hipLaunchKernelGGL(lstm_rec, dim3(16), dim3(1024), 0, stream,
                           (const short8*)wr1, (const f32x4*)xgb, h1b, cb1, hs1,
                           t0, TC, (size_t)T_ * HP_, t0);
    }
    hipLaunchKernelGGL(head_kernel, dim3(256), dim3(256), 0, stream,
                       h1b, W1, b1, W2, b2, W3, b3, (float*)d_out);
}